// Round 1
// baseline (2085.459 us; speedup 1.0000x reference)
//
#include <hip/hip_runtime.h>
#include <cstdint>
#include <cstddef>

#define NPTS 2048
#define BATCH 8
#define KNN 20
#define BIGF 3.402823466e38f

// ======================= sum of squares per point =======================
__global__ __launch_bounds__(256) void sq_kernel(const float* __restrict__ x, int lda, int F,
                                                 float* __restrict__ sq)
{
    int p = blockIdx.x * 256 + threadIdx.x;   // 0..16383
    const float* xp = x + (size_t)p * lda;
    float s = 0.f;
    for (int f = 0; f < F; ++f) { float v = xp[f]; s = fmaf(v, v, s); }
    sq[p] = s;
}

// ======================= pairwise distance GEMM =======================
// d2[bz][i][j] = sq_i + sq_j - 2*dot(x_i,x_j)   (per batch b0+bz)
__global__ __launch_bounds__(256) void dist_kernel(const float* __restrict__ x, int lda,
                                                   const float* __restrict__ sq,
                                                   float* __restrict__ d2, int F, int b0)
{
    __shared__ __align__(16) float As[8][132];
    __shared__ __align__(16) float Bs[8][132];
    const int b  = b0 + blockIdx.z;
    const int i0 = blockIdx.x * 128;
    const int j0 = blockIdx.y * 128;
    const float* xb  = x + (size_t)b * NPTS * lda;
    const float* sqb = sq + (size_t)b * NPTS;
    const int t  = threadIdx.x;
    const int tx = t & 15, ty = t >> 4;
    const int lrow = t >> 1, lkq = (t & 1) * 4;

    float acc[8][8];
#pragma unroll
    for (int r = 0; r < 8; ++r)
#pragma unroll
        for (int c = 0; c < 8; ++c) acc[r][c] = 0.f;

    for (int k0 = 0; k0 < F; k0 += 8) {
        const float* sa = xb + (size_t)(i0 + lrow) * lda + k0 + lkq;
        const float* sb = xb + (size_t)(j0 + lrow) * lda + k0 + lkq;
        if (k0 + 8 <= F) {
            float4 a4 = *reinterpret_cast<const float4*>(sa);
            float4 b4 = *reinterpret_cast<const float4*>(sb);
            As[lkq + 0][lrow] = a4.x; As[lkq + 1][lrow] = a4.y;
            As[lkq + 2][lrow] = a4.z; As[lkq + 3][lrow] = a4.w;
            Bs[lkq + 0][lrow] = b4.x; Bs[lkq + 1][lrow] = b4.y;
            Bs[lkq + 2][lrow] = b4.z; Bs[lkq + 3][lrow] = b4.w;
        } else {
#pragma unroll
            for (int q = 0; q < 4; ++q) {
                int kk = k0 + lkq + q;
                As[lkq + q][lrow] = (kk < F) ? sa[q] : 0.f;
                Bs[lkq + q][lrow] = (kk < F) ? sb[q] : 0.f;
            }
        }
        __syncthreads();
#pragma unroll
        for (int k = 0; k < 8; ++k) {
            float4 a0 = *reinterpret_cast<const float4*>(&As[k][ty * 4]);
            float4 a1 = *reinterpret_cast<const float4*>(&As[k][64 + ty * 4]);
            float4 c0 = *reinterpret_cast<const float4*>(&Bs[k][tx * 4]);
            float4 c1 = *reinterpret_cast<const float4*>(&Bs[k][64 + tx * 4]);
            float av[8] = {a0.x, a0.y, a0.z, a0.w, a1.x, a1.y, a1.z, a1.w};
            float bv[8] = {c0.x, c0.y, c0.z, c0.w, c1.x, c1.y, c1.z, c1.w};
#pragma unroll
            for (int r = 0; r < 8; ++r)
#pragma unroll
                for (int c = 0; c < 8; ++c) acc[r][c] = fmaf(av[r], bv[c], acc[r][c]);
        }
        __syncthreads();
    }

    float* db = d2 + (size_t)blockIdx.z * NPTS * NPTS;
#pragma unroll
    for (int r = 0; r < 8; ++r) {
        int i = i0 + ((r < 4) ? (ty * 4 + r) : (64 + ty * 4 + r - 4));
        float si = sqb[i];
#pragma unroll
        for (int cq = 0; cq < 2; ++cq) {
            int j = j0 + (cq ? 64 : 0) + tx * 4;
            float4 o;
            o.x = si + sqb[j + 0] - 2.f * acc[r][cq * 4 + 0];
            o.y = si + sqb[j + 1] - 2.f * acc[r][cq * 4 + 1];
            o.z = si + sqb[j + 2] - 2.f * acc[r][cq * 4 + 2];
            o.w = si + sqb[j + 3] - 2.f * acc[r][cq * 4 + 3];
            *reinterpret_cast<float4*>(&db[(size_t)i * NPTS + j]) = o;
        }
    }
}

// ======================= top-20 (iterative argmin, ties -> lower index) =======================
__global__ __launch_bounds__(256) void select_kernel(const float* __restrict__ d2,
                                                     int* __restrict__ idx, int b0)
{
    const int i  = blockIdx.x;
    const int bz = blockIdx.y;
    const int t  = threadIdx.x;
    const float* row = d2 + ((size_t)bz * NPTS + i) * NPTS;
    float v[8];
#pragma unroll
    for (int s = 0; s < 8; ++s) v[s] = row[s * 256 + t];

    __shared__ float wv[4];
    __shared__ int   wj[4];
    __shared__ int   winner;
    int* out = idx + ((size_t)(b0 + bz) * NPTS + i) * KNN;

    for (int it = 0; it < KNN; ++it) {
        float bv = v[0]; int bj = t;
#pragma unroll
        for (int s = 1; s < 8; ++s) {
            float vv = v[s];
            if (vv < bv) { bv = vv; bj = s * 256 + t; }
        }
#pragma unroll
        for (int o = 1; o < 64; o <<= 1) {
            float ov = __shfl_xor(bv, o, 64);
            int   oj = __shfl_xor(bj, o, 64);
            if (ov < bv || (ov == bv && oj < bj)) { bv = ov; bj = oj; }
        }
        if ((t & 63) == 0) { wv[t >> 6] = bv; wj[t >> 6] = bj; }
        __syncthreads();
        if (t == 0) {
            float fv = wv[0]; int fj = wj[0];
#pragma unroll
            for (int q = 1; q < 4; ++q)
                if (wv[q] < fv || (wv[q] == fv && wj[q] < fj)) { fv = wv[q]; fj = wj[q]; }
            out[it] = fj;
            winner  = fj;
        }
        __syncthreads();
        const int fj = winner;
        if ((fj & 255) == t) v[fj >> 8] = BIGF;
    }
}

// ======================= generic small GEMM: C[M,Nc] = A[M,F] @ B[F,Nc] =======================
__global__ __launch_bounds__(256) void gemm64_kernel(const float* __restrict__ A, int lda, int F,
                                                     const float* __restrict__ Bw, int ldb,
                                                     float* __restrict__ C, int ldc)
{
    __shared__ float As[16][65];
    __shared__ float Bs[16][65];
    const int i0 = blockIdx.x * 64, j0 = blockIdx.y * 64;
    const int t = threadIdx.x, tx = t & 15, ty = t >> 4;
    float acc[4][4];
#pragma unroll
    for (int r = 0; r < 4; ++r)
#pragma unroll
        for (int c = 0; c < 4; ++c) acc[r][c] = 0.f;
    const int arow = t >> 2, akq = (t & 3) * 4;
    const int bk = t >> 4, bj = (t & 15) * 4;
    for (int k0 = 0; k0 < F; k0 += 16) {
#pragma unroll
        for (int q = 0; q < 4; ++q) {
            int kk = k0 + akq + q;
            As[akq + q][arow] = (kk < F) ? A[(size_t)(i0 + arow) * lda + kk] : 0.f;
        }
        {
            int kk = k0 + bk;
#pragma unroll
            for (int q = 0; q < 4; ++q)
                Bs[bk][bj + q] = (kk < F) ? Bw[(size_t)kk * ldb + j0 + bj + q] : 0.f;
        }
        __syncthreads();
#pragma unroll
        for (int k = 0; k < 16; ++k) {
            float a[4], bb[4];
#pragma unroll
            for (int r = 0; r < 4; ++r) a[r] = As[k][ty * 4 + r];
#pragma unroll
            for (int c = 0; c < 4; ++c) bb[c] = Bs[k][tx * 4 + c];
#pragma unroll
            for (int r = 0; r < 4; ++r)
#pragma unroll
                for (int c = 0; c < 4; ++c) acc[r][c] = fmaf(a[r], bb[c], acc[r][c]);
        }
        __syncthreads();
    }
#pragma unroll
    for (int r = 0; r < 4; ++r)
#pragma unroll
        for (int c = 0; c < 4; ++c)
            C[(size_t)(i0 + ty * 4 + r) * ldc + j0 + tx * 4 + c] = acc[r][c];
}

// ======================= EdgeConv aggregate: lrelu(bn((a_i-b_i) + max_k b_j)) =======================
__global__ void aggregate_kernel(const float* __restrict__ apart, const float* __restrict__ bpart,
                                 const int* __restrict__ idx,
                                 const float* __restrict__ g, const float* __restrict__ be,
                                 const float* __restrict__ mu, const float* __restrict__ var,
                                 float* __restrict__ out, int Fout)
{
    const int p = blockIdx.x;          // global point 0..16383
    const int b = p >> 11;             // /2048
    const int f = threadIdx.x;
    __shared__ int nb[KNN];
    if (f < KNN) nb[f] = idx[(size_t)p * KNN + f];
    __syncthreads();
    float av = apart[(size_t)p * Fout + f];
    float bv = bpart[(size_t)p * Fout + f];
    const float* bb = bpart + ((size_t)b << 11) * Fout;
    float m = -BIGF;
#pragma unroll 4
    for (int k = 0; k < KNN; ++k) m = fmaxf(m, bb[(size_t)nb[k] * Fout + f]);
    float vv = av - bv + m;
    float s  = g[f] * rsqrtf(var[f] + 1e-5f);
    float y  = vv * s + (be[f] - mu[f] * s);
    y = (y >= 0.f) ? y : 0.2f * y;
    out[(size_t)p * 512 + f] = y;      // xcat, ld 512 (column offset in `out` base)
}

// ======================= Wm GEMM + BN + lrelu + fused max/sum partial pooling =======================
__global__ __launch_bounds__(256) void wm_pool_kernel(const float* __restrict__ A,   // xcat [16384,512]
                                                      const float* __restrict__ Bw,  // Wm [512,1024]
                                                      const float* __restrict__ g,
                                                      const float* __restrict__ be,
                                                      const float* __restrict__ mu,
                                                      const float* __restrict__ var,
                                                      float* __restrict__ partmax,
                                                      float* __restrict__ partsum)
{
    __shared__ __align__(16) float As[8][132];
    __shared__ __align__(16) float Bs[8][132];
    __shared__ float red[16][129];
    const int i0 = blockIdx.x * 128;
    const int j0 = blockIdx.y * 128;
    const int t  = threadIdx.x;
    const int tx = t & 15, ty = t >> 4;
    const int lrow = t >> 1, lkq = (t & 1) * 4;
    const int bk = t >> 5, bj = (t & 31) * 4;

    float acc[8][8];
#pragma unroll
    for (int r = 0; r < 8; ++r)
#pragma unroll
        for (int c = 0; c < 8; ++c) acc[r][c] = 0.f;

    for (int k0 = 0; k0 < 512; k0 += 8) {
        float4 a4 = *reinterpret_cast<const float4*>(A + (size_t)(i0 + lrow) * 512 + k0 + lkq);
        As[lkq + 0][lrow] = a4.x; As[lkq + 1][lrow] = a4.y;
        As[lkq + 2][lrow] = a4.z; As[lkq + 3][lrow] = a4.w;
        float4 b4 = *reinterpret_cast<const float4*>(Bw + (size_t)(k0 + bk) * 1024 + j0 + bj);
        *reinterpret_cast<float4*>(&Bs[bk][bj]) = b4;
        __syncthreads();
#pragma unroll
        for (int k = 0; k < 8; ++k) {
            float4 a0 = *reinterpret_cast<const float4*>(&As[k][ty * 4]);
            float4 a1 = *reinterpret_cast<const float4*>(&As[k][64 + ty * 4]);
            float4 c0 = *reinterpret_cast<const float4*>(&Bs[k][tx * 4]);
            float4 c1 = *reinterpret_cast<const float4*>(&Bs[k][64 + tx * 4]);
            float av[8] = {a0.x, a0.y, a0.z, a0.w, a1.x, a1.y, a1.z, a1.w};
            float bv[8] = {c0.x, c0.y, c0.z, c0.w, c1.x, c1.y, c1.z, c1.w};
#pragma unroll
            for (int r = 0; r < 8; ++r)
#pragma unroll
                for (int c = 0; c < 8; ++c) acc[r][c] = fmaf(av[r], bv[c], acc[r][c]);
        }
        __syncthreads();
    }

    float sc[8], sh[8];
#pragma unroll
    for (int cc = 0; cc < 8; ++cc) {
        int j = j0 + ((cc < 4) ? 0 : 64) + tx * 4 + (cc & 3);
        float s = g[j] * rsqrtf(var[j] + 1e-5f);
        sc[cc] = s; sh[cc] = be[j] - mu[j] * s;
    }
#pragma unroll
    for (int r = 0; r < 8; ++r)
#pragma unroll
        for (int cc = 0; cc < 8; ++cc) {
            float y = fmaf(acc[r][cc], sc[cc], sh[cc]);
            acc[r][cc] = (y >= 0.f) ? y : 0.2f * y;
        }

    const int b  = i0 >> 11;
    const int rb = (i0 & 2047) >> 7;
#pragma unroll
    for (int cc = 0; cc < 8; ++cc) {
        float m = acc[0][cc];
#pragma unroll
        for (int r = 1; r < 8; ++r) m = fmaxf(m, acc[r][cc]);
        red[ty][((cc < 4) ? 0 : 64) + tx * 4 + (cc & 3)] = m;
    }
    __syncthreads();
    if (t < 128) {
        float m = red[0][t];
#pragma unroll
        for (int q = 1; q < 16; ++q) m = fmaxf(m, red[q][t]);
        partmax[((size_t)b * 16 + rb) * 1024 + j0 + t] = m;
    }
    __syncthreads();
#pragma unroll
    for (int cc = 0; cc < 8; ++cc) {
        float s = acc[0][cc];
#pragma unroll
        for (int r = 1; r < 8; ++r) s += acc[r][cc];
        red[ty][((cc < 4) ? 0 : 64) + tx * 4 + (cc & 3)] = s;
    }
    __syncthreads();
    if (t < 128) {
        float s = red[0][t];
#pragma unroll
        for (int q = 1; q < 16; ++q) s += red[q][t];
        partsum[((size_t)b * 16 + rb) * 1024 + j0 + t] = s;
    }
}

// ======================= pooling reduce =======================
__global__ __launch_bounds__(256) void pool2_kernel(const float* __restrict__ partmax,
                                                    const float* __restrict__ partsum,
                                                    float* __restrict__ pooled)
{
    const int c = blockIdx.x * 256 + threadIdx.x;   // 0..1023
    const int b = blockIdx.y;
    float m = -BIGF, s = 0.f;
    for (int rb = 0; rb < 16; ++rb) {
        m = fmaxf(m, partmax[((size_t)b * 16 + rb) * 1024 + c]);
        s += partsum[((size_t)b * 16 + rb) * 1024 + c];
    }
    pooled[(size_t)b * 2048 + c] = m;
    pooled[(size_t)b * 2048 + 1024 + c] = s * (1.f / 2048.f);
}

// ======================= tail FCs =======================
__global__ __launch_bounds__(512) void fc1_kernel(const float* __restrict__ pooled,
                                                  const float* __restrict__ Wa,
                                                  const float* __restrict__ g, const float* __restrict__ be,
                                                  const float* __restrict__ mu, const float* __restrict__ var,
                                                  float* __restrict__ t1)
{
    const int b = blockIdx.x, c = threadIdx.x;   // 512 threads
    __shared__ float sp[2048];
    for (int k = c; k < 2048; k += 512) sp[k] = pooled[(size_t)b * 2048 + k];
    __syncthreads();
    float acc = 0.f;
#pragma unroll 8
    for (int k = 0; k < 2048; ++k) acc = fmaf(sp[k], Wa[(size_t)k * 512 + c], acc);
    float s = g[c] * rsqrtf(var[c] + 1e-5f);
    float y = acc * s + (be[c] - mu[c] * s);
    t1[(size_t)b * 512 + c] = (y >= 0.f) ? y : 0.2f * y;
}

__global__ __launch_bounds__(256) void fc2_kernel(const float* __restrict__ t1,
                                                  const float* __restrict__ Wb,
                                                  const float* __restrict__ bias_b,
                                                  const float* __restrict__ g, const float* __restrict__ be,
                                                  const float* __restrict__ mu, const float* __restrict__ var,
                                                  float* __restrict__ t2)
{
    const int b = blockIdx.x, c = threadIdx.x;   // 256 threads
    __shared__ float sp[512];
    for (int k = c; k < 512; k += 256) sp[k] = t1[(size_t)b * 512 + k];
    __syncthreads();
    float acc = 0.f;
#pragma unroll 8
    for (int k = 0; k < 512; ++k) acc = fmaf(sp[k], Wb[(size_t)k * 256 + c], acc);
    acc += bias_b[c];
    float s = g[c] * rsqrtf(var[c] + 1e-5f);
    float y = acc * s + (be[c] - mu[c] * s);
    t2[(size_t)b * 256 + c] = (y >= 0.f) ? y : 0.2f * y;
}

__global__ __launch_bounds__(64) void fc3_kernel(const float* __restrict__ t2,
                                                 const float* __restrict__ Wc,
                                                 const float* __restrict__ bias_c,
                                                 float* __restrict__ out)
{
    const int b = blockIdx.x, c = threadIdx.x;
    __shared__ float sp[256];
    for (int k = c; k < 256; k += 64) sp[k] = t2[(size_t)b * 256 + k];
    __syncthreads();
    if (c < 40) {
        float acc = 0.f;
#pragma unroll 8
        for (int k = 0; k < 256; ++k) acc = fmaf(sp[k], Wc[(size_t)k * 40 + c], acc);
        out[(size_t)b * 40 + c] = acc + bias_c[c];
    }
}

// ======================= launch =======================
extern "C" void kernel_launch(void* const* d_in, const int* in_sizes, int n_in,
                              void* d_out, int out_size, void* d_ws, size_t ws_size,
                              hipStream_t stream)
{
    const float* pos = (const float*)d_in[0];
    const float* W1 = (const float*)d_in[1];
    const float* g1 = (const float*)d_in[2];  const float* be1 = (const float*)d_in[3];
    const float* mu1 = (const float*)d_in[4]; const float* va1 = (const float*)d_in[5];
    const float* W2 = (const float*)d_in[6];
    const float* g2 = (const float*)d_in[7];  const float* be2 = (const float*)d_in[8];
    const float* mu2 = (const float*)d_in[9]; const float* va2 = (const float*)d_in[10];
    const float* W3 = (const float*)d_in[11];
    const float* g3 = (const float*)d_in[12]; const float* be3 = (const float*)d_in[13];
    const float* mu3 = (const float*)d_in[14];const float* va3 = (const float*)d_in[15];
    const float* W4 = (const float*)d_in[16];
    const float* g4 = (const float*)d_in[17]; const float* be4 = (const float*)d_in[18];
    const float* mu4 = (const float*)d_in[19];const float* va4 = (const float*)d_in[20];
    const float* Wm = (const float*)d_in[21];
    const float* gm = (const float*)d_in[22]; const float* bem = (const float*)d_in[23];
    const float* mum = (const float*)d_in[24];const float* vam = (const float*)d_in[25];
    const float* Wa = (const float*)d_in[26];
    const float* ga = (const float*)d_in[27]; const float* bea = (const float*)d_in[28];
    const float* mua = (const float*)d_in[29];const float* vaa = (const float*)d_in[30];
    const float* Wb = (const float*)d_in[31];
    const float* gb = (const float*)d_in[32]; const float* beb = (const float*)d_in[33];
    const float* mub = (const float*)d_in[34];const float* vab = (const float*)d_in[35];
    const float* bias_b = (const float*)d_in[36];
    const float* Wc = (const float*)d_in[37];
    const float* bias_c = (const float*)d_in[38];

    char* ws = (char*)d_ws;
    size_t off = 0;
    auto alloc = [&](size_t bytes) -> void* {
        void* p = ws + off;
        off += (bytes + 255) & ~(size_t)255;
        return p;
    };
    float* xcat    = (float*)alloc((size_t)16384 * 512 * 4);
    float* sq      = (float*)alloc((size_t)16384 * 4);
    int*   idx     = (int*)  alloc((size_t)16384 * KNN * 4);
    float* apart   = (float*)alloc((size_t)16384 * 256 * 4);
    float* bpart   = (float*)alloc((size_t)16384 * 256 * 4);
    float* partmax = (float*)alloc((size_t)8 * 16 * 1024 * 4);
    float* partsum = (float*)alloc((size_t)8 * 16 * 1024 * 4);
    float* pooled  = (float*)alloc((size_t)8 * 2048 * 4);
    float* t1      = (float*)alloc((size_t)8 * 512 * 4);
    float* t2      = (float*)alloc((size_t)8 * 256 * 4);
    const size_t fixed = off;
    const size_t per_b = (size_t)NPTS * NPTS * 4;

    int CB; float* d2;
    if      (ws_size >= fixed + 8 * per_b) { CB = 8; d2 = (float*)(ws + fixed); }
    else if (ws_size >= fixed + 4 * per_b) { CB = 4; d2 = (float*)(ws + fixed); }
    else if (ws_size >= fixed + 2 * per_b) { CB = 2; d2 = (float*)(ws + fixed); }
    else { CB = 2; d2 = apart; }   // apart+bpart are contiguous, dead during dist/select phase

    struct LayerDesc {
        const float* xin; int lda; int F; int Fout;
        float* xout; const float* W;
        const float* g; const float* be; const float* mu; const float* va;
    };
    LayerDesc Ls[4] = {
        { pos,        3,   3,   64,  xcat + 0,   W1, g1, be1, mu1, va1 },
        { xcat + 0,   512, 64,  64,  xcat + 64,  W2, g2, be2, mu2, va2 },
        { xcat + 64,  512, 64,  128, xcat + 128, W3, g3, be3, mu3, va3 },
        { xcat + 128, 512, 128, 256, xcat + 256, W4, g4, be4, mu4, va4 },
    };

    for (int L = 0; L < 4; ++L) {
        const LayerDesc& ld = Ls[L];
        sq_kernel<<<64, 256, 0, stream>>>(ld.xin, ld.lda, ld.F, sq);
        for (int b0 = 0; b0 < BATCH; b0 += CB) {
            int cb = (BATCH - b0 < CB) ? (BATCH - b0) : CB;
            dist_kernel<<<dim3(16, 16, cb), 256, 0, stream>>>(ld.xin, ld.lda, sq, d2, ld.F, b0);
            select_kernel<<<dim3(NPTS, cb), 256, 0, stream>>>(d2, idx, b0);
        }
        gemm64_kernel<<<dim3(256, ld.Fout / 64), 256, 0, stream>>>(
            ld.xin, ld.lda, ld.F, ld.W, ld.Fout, apart, ld.Fout);
        gemm64_kernel<<<dim3(256, ld.Fout / 64), 256, 0, stream>>>(
            ld.xin, ld.lda, ld.F, ld.W + (size_t)ld.F * ld.Fout, ld.Fout, bpart, ld.Fout);
        aggregate_kernel<<<16384, ld.Fout, 0, stream>>>(
            apart, bpart, idx, ld.g, ld.be, ld.mu, ld.va, ld.xout, ld.Fout);
    }

    wm_pool_kernel<<<dim3(128, 8), 256, 0, stream>>>(xcat, Wm, gm, bem, mum, vam, partmax, partsum);
    pool2_kernel<<<dim3(4, 8), 256, 0, stream>>>(partmax, partsum, pooled);
    fc1_kernel<<<8, 512, 0, stream>>>(pooled, Wa, ga, bea, mua, vaa, t1);
    fc2_kernel<<<8, 256, 0, stream>>>(t1, Wb, bias_b, gb, beb, mub, vab, t2);
    fc3_kernel<<<8, 64, 0, stream>>>(t2, Wc, bias_c, (float*)d_out);
}

// Round 2
// 1412.341 us; speedup vs baseline: 1.4766x; 1.4766x over previous
//
#include <hip/hip_runtime.h>
#include <cstdint>
#include <cstddef>

#define NPTS 2048
#define BATCH 8
#define KNN 20
#define BIGF 3.402823466e38f

// ======================= sum of squares per point =======================
__global__ __launch_bounds__(256) void sq_kernel(const float* __restrict__ x, int lda, int F,
                                                 float* __restrict__ sq)
{
    int p = blockIdx.x * 256 + threadIdx.x;   // 0..16383
    const float* xp = x + (size_t)p * lda;
    float s = 0.f;
    for (int f = 0; f < F; ++f) { float v = xp[f]; s = fmaf(v, v, s); }
    sq[p] = s;
}

// ======================= pairwise distance GEMM =======================
// d2[bz][i][j] = sq_i + sq_j - 2*dot(x_i,x_j)   (per batch b0+bz)
__global__ __launch_bounds__(256) void dist_kernel(const float* __restrict__ x, int lda,
                                                   const float* __restrict__ sq,
                                                   float* __restrict__ d2, int F, int b0)
{
    __shared__ __align__(16) float As[8][132];
    __shared__ __align__(16) float Bs[8][132];
    const int b  = b0 + blockIdx.z;
    const int i0 = blockIdx.x * 128;
    const int j0 = blockIdx.y * 128;
    const float* xb  = x + (size_t)b * NPTS * lda;
    const float* sqb = sq + (size_t)b * NPTS;
    const int t  = threadIdx.x;
    const int tx = t & 15, ty = t >> 4;
    const int lrow = t >> 1, lkq = (t & 1) * 4;

    float acc[8][8];
#pragma unroll
    for (int r = 0; r < 8; ++r)
#pragma unroll
        for (int c = 0; c < 8; ++c) acc[r][c] = 0.f;

    for (int k0 = 0; k0 < F; k0 += 8) {
        const float* sa = xb + (size_t)(i0 + lrow) * lda + k0 + lkq;
        const float* sb = xb + (size_t)(j0 + lrow) * lda + k0 + lkq;
        if (k0 + 8 <= F) {
            float4 a4 = *reinterpret_cast<const float4*>(sa);
            float4 b4 = *reinterpret_cast<const float4*>(sb);
            As[lkq + 0][lrow] = a4.x; As[lkq + 1][lrow] = a4.y;
            As[lkq + 2][lrow] = a4.z; As[lkq + 3][lrow] = a4.w;
            Bs[lkq + 0][lrow] = b4.x; Bs[lkq + 1][lrow] = b4.y;
            Bs[lkq + 2][lrow] = b4.z; Bs[lkq + 3][lrow] = b4.w;
        } else {
#pragma unroll
            for (int q = 0; q < 4; ++q) {
                int kk = k0 + lkq + q;
                As[lkq + q][lrow] = (kk < F) ? sa[q] : 0.f;
                Bs[lkq + q][lrow] = (kk < F) ? sb[q] : 0.f;
            }
        }
        __syncthreads();
#pragma unroll
        for (int k = 0; k < 8; ++k) {
            float4 a0 = *reinterpret_cast<const float4*>(&As[k][ty * 4]);
            float4 a1 = *reinterpret_cast<const float4*>(&As[k][64 + ty * 4]);
            float4 c0 = *reinterpret_cast<const float4*>(&Bs[k][tx * 4]);
            float4 c1 = *reinterpret_cast<const float4*>(&Bs[k][64 + tx * 4]);
            float av[8] = {a0.x, a0.y, a0.z, a0.w, a1.x, a1.y, a1.z, a1.w};
            float bv[8] = {c0.x, c0.y, c0.z, c0.w, c1.x, c1.y, c1.z, c1.w};
#pragma unroll
            for (int r = 0; r < 8; ++r)
#pragma unroll
                for (int c = 0; c < 8; ++c) acc[r][c] = fmaf(av[r], bv[c], acc[r][c]);
        }
        __syncthreads();
    }

    float* db = d2 + (size_t)blockIdx.z * NPTS * NPTS;
#pragma unroll
    for (int r = 0; r < 8; ++r) {
        int i = i0 + ((r < 4) ? (ty * 4 + r) : (64 + ty * 4 + r - 4));
        float si = sqb[i];
#pragma unroll
        for (int cq = 0; cq < 2; ++cq) {
            int j = j0 + (cq ? 64 : 0) + tx * 4;
            float4 o;
            o.x = si + sqb[j + 0] - 2.f * acc[r][cq * 4 + 0];
            o.y = si + sqb[j + 1] - 2.f * acc[r][cq * 4 + 1];
            o.z = si + sqb[j + 2] - 2.f * acc[r][cq * 4 + 2];
            o.w = si + sqb[j + 3] - 2.f * acc[r][cq * 4 + 3];
            *reinterpret_cast<float4*>(&db[(size_t)i * NPTS + j]) = o;
        }
    }
}

// ======================= top-20 via 4-pass radix select =======================
// Picks the 20 smallest d2 (ties -> lower index), set-equivalent to lax.top_k(-d2, 20).
// Output order within the 20 is arbitrary (downstream max-aggregation is order-invariant).
__global__ __launch_bounds__(256) void select_kernel(const float* __restrict__ d2,
                                                     int* __restrict__ idx, int b0)
{
    const int i  = blockIdx.x;
    const int bz = blockIdx.y;
    const int t  = threadIdx.x;
    const float* row = d2 + ((size_t)bz * NPTS + i) * NPTS;

    // order-preserving key: ascending uint == ascending float
    uint32_t key[8];
#pragma unroll
    for (int s = 0; s < 8; ++s) {
        uint32_t u = __float_as_uint(row[s * 256 + t]);
        key[s] = (u & 0x80000000u) ? ~u : (u | 0x80000000u);
    }

    __shared__ uint32_t hist[256];
    __shared__ uint32_t cum[256];
    __shared__ int ties[2048];
    __shared__ uint32_t sel_bin, sel_lo;
    __shared__ int cnt, tcnt;

    uint32_t pfx = 0;   // value of selected bits [31:shift], right-aligned
    uint32_t clt = 0;   // # keys strictly below the current prefix range

#pragma unroll
    for (int pass = 0; pass < 4; ++pass) {
        const int shift = 24 - 8 * pass;
        const int hs = (pass == 0) ? 0 : (shift + 8);   // guarded: never >= 32
        hist[t] = 0;
        if (t == 0 && pass == 0) { cnt = 0; tcnt = 0; }
        __syncthreads();
#pragma unroll
        for (int s = 0; s < 8; ++s) {
            uint32_t k = key[s];
            bool match = (pass == 0) ? true : ((k >> hs) == pfx);
            if (match) atomicAdd(&hist[(k >> shift) & 255], 1u);
        }
        __syncthreads();
        if (t < 64) {
            uint32_t h0 = hist[t * 4 + 0], h1 = hist[t * 4 + 1];
            uint32_t h2 = hist[t * 4 + 2], h3 = hist[t * 4 + 3];
            uint32_t s0 = h0, s1 = s0 + h1, s2 = s1 + h2, s3 = s2 + h3;
            uint32_t run = s3;
#pragma unroll
            for (int o = 1; o < 64; o <<= 1) {
                uint32_t v = __shfl_up(run, o, 64);
                if (t >= o) run += v;
            }
            uint32_t excl = run - s3;   // exclusive prefix over 4-bin groups
            cum[t * 4 + 0] = excl;
            cum[t * 4 + 1] = excl + s0;
            cum[t * 4 + 2] = excl + s1;
            cum[t * 4 + 3] = excl + s2;
        }
        __syncthreads();
        {
            uint32_t lo = clt + cum[t];
            uint32_t hi = lo + hist[t];
            if (lo < (uint32_t)KNN && (uint32_t)KNN <= hi) { sel_bin = (uint32_t)t; sel_lo = lo; }
        }
        __syncthreads();
        pfx = (pfx << 8) | sel_bin;   // read after barrier; rewritten only after 2 more barriers
        clt = sel_lo;
    }

    // pfx == key value of the rank-20 element; clt == # strictly smaller
    int* out = idx + ((size_t)(b0 + bz) * NPTS + i) * KNN;
    const uint32_t ustar = pfx;
#pragma unroll
    for (int s = 0; s < 8; ++s) {
        uint32_t k = key[s];
        if (k < ustar) {
            int p = atomicAdd(&cnt, 1);
            out[p] = s * 256 + t;
        } else if (k == ustar) {
            int p = atomicAdd(&tcnt, 1);
            ties[p] = s * 256 + t;
        }
    }
    __syncthreads();
    const int m = KNN - (int)clt;    // how many ties to keep (>=1)
    const int T = tcnt;
    if (T == m) {                    // common case: exact fill, any order
        if (t < m) out[clt + t] = ties[t];
    } else if (t == 0) {             // rare: choose m lowest indices among T ties
        for (int it = 0; it < m; ++it) {
            int best = 0x7fffffff, bq = 0;
            for (int q = 0; q < T; ++q) { int v = ties[q]; if (v < best) { best = v; bq = q; } }
            ties[bq] = 0x7fffffff;
            out[clt + it] = best;
        }
    }
}

// ======================= generic small GEMM: C[M,Nc] = A[M,F] @ B[F,Nc] =======================
__global__ __launch_bounds__(256) void gemm64_kernel(const float* __restrict__ A, int lda, int F,
                                                     const float* __restrict__ Bw, int ldb,
                                                     float* __restrict__ C, int ldc)
{
    __shared__ float As[16][65];
    __shared__ float Bs[16][65];
    const int i0 = blockIdx.x * 64, j0 = blockIdx.y * 64;
    const int t = threadIdx.x, tx = t & 15, ty = t >> 4;
    float acc[4][4];
#pragma unroll
    for (int r = 0; r < 4; ++r)
#pragma unroll
        for (int c = 0; c < 4; ++c) acc[r][c] = 0.f;
    const int arow = t >> 2, akq = (t & 3) * 4;
    const int bk = t >> 4, bj = (t & 15) * 4;
    for (int k0 = 0; k0 < F; k0 += 16) {
#pragma unroll
        for (int q = 0; q < 4; ++q) {
            int kk = k0 + akq + q;
            As[akq + q][arow] = (kk < F) ? A[(size_t)(i0 + arow) * lda + kk] : 0.f;
        }
        {
            int kk = k0 + bk;
#pragma unroll
            for (int q = 0; q < 4; ++q)
                Bs[bk][bj + q] = (kk < F) ? Bw[(size_t)kk * ldb + j0 + bj + q] : 0.f;
        }
        __syncthreads();
#pragma unroll
        for (int k = 0; k < 16; ++k) {
            float a[4], bb[4];
#pragma unroll
            for (int r = 0; r < 4; ++r) a[r] = As[k][ty * 4 + r];
#pragma unroll
            for (int c = 0; c < 4; ++c) bb[c] = Bs[k][tx * 4 + c];
#pragma unroll
            for (int r = 0; r < 4; ++r)
#pragma unroll
                for (int c = 0; c < 4; ++c) acc[r][c] = fmaf(a[r], bb[c], acc[r][c]);
        }
        __syncthreads();
    }
#pragma unroll
    for (int r = 0; r < 4; ++r)
#pragma unroll
        for (int c = 0; c < 4; ++c)
            C[(size_t)(i0 + ty * 4 + r) * ldc + j0 + tx * 4 + c] = acc[r][c];
}

// ======================= EdgeConv aggregate: lrelu(bn((a_i-b_i) + max_k b_j)) =======================
__global__ void aggregate_kernel(const float* __restrict__ apart, const float* __restrict__ bpart,
                                 const int* __restrict__ idx,
                                 const float* __restrict__ g, const float* __restrict__ be,
                                 const float* __restrict__ mu, const float* __restrict__ var,
                                 float* __restrict__ out, int Fout)
{
    const int p = blockIdx.x;          // global point 0..16383
    const int b = p >> 11;             // /2048
    const int f = threadIdx.x;
    __shared__ int nb[KNN];
    if (f < KNN) nb[f] = idx[(size_t)p * KNN + f];
    __syncthreads();
    float av = apart[(size_t)p * Fout + f];
    float bv = bpart[(size_t)p * Fout + f];
    const float* bb = bpart + ((size_t)b << 11) * Fout;
    float m = -BIGF;
#pragma unroll 4
    for (int k = 0; k < KNN; ++k) m = fmaxf(m, bb[(size_t)nb[k] * Fout + f]);
    float vv = av - bv + m;
    float s  = g[f] * rsqrtf(var[f] + 1e-5f);
    float y  = vv * s + (be[f] - mu[f] * s);
    y = (y >= 0.f) ? y : 0.2f * y;
    out[(size_t)p * 512 + f] = y;      // xcat, ld 512 (column offset in `out` base)
}

// ======================= Wm GEMM + BN + lrelu + fused max/sum partial pooling =======================
__global__ __launch_bounds__(256) void wm_pool_kernel(const float* __restrict__ A,   // xcat [16384,512]
                                                      const float* __restrict__ Bw,  // Wm [512,1024]
                                                      const float* __restrict__ g,
                                                      const float* __restrict__ be,
                                                      const float* __restrict__ mu,
                                                      const float* __restrict__ var,
                                                      float* __restrict__ partmax,
                                                      float* __restrict__ partsum)
{
    __shared__ __align__(16) float As[8][132];
    __shared__ __align__(16) float Bs[8][132];
    __shared__ float red[16][129];
    const int i0 = blockIdx.x * 128;
    const int j0 = blockIdx.y * 128;
    const int t  = threadIdx.x;
    const int tx = t & 15, ty = t >> 4;
    const int lrow = t >> 1, lkq = (t & 1) * 4;
    const int bk = t >> 5, bj = (t & 31) * 4;

    float acc[8][8];
#pragma unroll
    for (int r = 0; r < 8; ++r)
#pragma unroll
        for (int c = 0; c < 8; ++c) acc[r][c] = 0.f;

    for (int k0 = 0; k0 < 512; k0 += 8) {
        float4 a4 = *reinterpret_cast<const float4*>(A + (size_t)(i0 + lrow) * 512 + k0 + lkq);
        As[lkq + 0][lrow] = a4.x; As[lkq + 1][lrow] = a4.y;
        As[lkq + 2][lrow] = a4.z; As[lkq + 3][lrow] = a4.w;
        float4 b4 = *reinterpret_cast<const float4*>(Bw + (size_t)(k0 + bk) * 1024 + j0 + bj);
        *reinterpret_cast<float4*>(&Bs[bk][bj]) = b4;
        __syncthreads();
#pragma unroll
        for (int k = 0; k < 8; ++k) {
            float4 a0 = *reinterpret_cast<const float4*>(&As[k][ty * 4]);
            float4 a1 = *reinterpret_cast<const float4*>(&As[k][64 + ty * 4]);
            float4 c0 = *reinterpret_cast<const float4*>(&Bs[k][tx * 4]);
            float4 c1 = *reinterpret_cast<const float4*>(&Bs[k][64 + tx * 4]);
            float av[8] = {a0.x, a0.y, a0.z, a0.w, a1.x, a1.y, a1.z, a1.w};
            float bv[8] = {c0.x, c0.y, c0.z, c0.w, c1.x, c1.y, c1.z, c1.w};
#pragma unroll
            for (int r = 0; r < 8; ++r)
#pragma unroll
                for (int c = 0; c < 8; ++c) acc[r][c] = fmaf(av[r], bv[c], acc[r][c]);
        }
        __syncthreads();
    }

    float sc[8], sh[8];
#pragma unroll
    for (int cc = 0; cc < 8; ++cc) {
        int j = j0 + ((cc < 4) ? 0 : 64) + tx * 4 + (cc & 3);
        float s = g[j] * rsqrtf(var[j] + 1e-5f);
        sc[cc] = s; sh[cc] = be[j] - mu[j] * s;
    }
#pragma unroll
    for (int r = 0; r < 8; ++r)
#pragma unroll
        for (int cc = 0; cc < 8; ++cc) {
            float y = fmaf(acc[r][cc], sc[cc], sh[cc]);
            acc[r][cc] = (y >= 0.f) ? y : 0.2f * y;
        }

    const int b  = i0 >> 11;
    const int rb = (i0 & 2047) >> 7;
#pragma unroll
    for (int cc = 0; cc < 8; ++cc) {
        float m = acc[0][cc];
#pragma unroll
        for (int r = 1; r < 8; ++r) m = fmaxf(m, acc[r][cc]);
        red[ty][((cc < 4) ? 0 : 64) + tx * 4 + (cc & 3)] = m;
    }
    __syncthreads();
    if (t < 128) {
        float m = red[0][t];
#pragma unroll
        for (int q = 1; q < 16; ++q) m = fmaxf(m, red[q][t]);
        partmax[((size_t)b * 16 + rb) * 1024 + j0 + t] = m;
    }
    __syncthreads();
#pragma unroll
    for (int cc = 0; cc < 8; ++cc) {
        float s = acc[0][cc];
#pragma unroll
        for (int r = 1; r < 8; ++r) s += acc[r][cc];
        red[ty][((cc < 4) ? 0 : 64) + tx * 4 + (cc & 3)] = s;
    }
    __syncthreads();
    if (t < 128) {
        float s = red[0][t];
#pragma unroll
        for (int q = 1; q < 16; ++q) s += red[q][t];
        partsum[((size_t)b * 16 + rb) * 1024 + j0 + t] = s;
    }
}

// ======================= pooling reduce =======================
__global__ __launch_bounds__(256) void pool2_kernel(const float* __restrict__ partmax,
                                                    const float* __restrict__ partsum,
                                                    float* __restrict__ pooled)
{
    const int c = blockIdx.x * 256 + threadIdx.x;   // 0..1023
    const int b = blockIdx.y;
    float m = -BIGF, s = 0.f;
    for (int rb = 0; rb < 16; ++rb) {
        m = fmaxf(m, partmax[((size_t)b * 16 + rb) * 1024 + c]);
        s += partsum[((size_t)b * 16 + rb) * 1024 + c];
    }
    pooled[(size_t)b * 2048 + c] = m;
    pooled[(size_t)b * 2048 + 1024 + c] = s * (1.f / 2048.f);
}

// ======================= tail FCs =======================
__global__ __launch_bounds__(512) void fc1_kernel(const float* __restrict__ pooled,
                                                  const float* __restrict__ Wa,
                                                  const float* __restrict__ g, const float* __restrict__ be,
                                                  const float* __restrict__ mu, const float* __restrict__ var,
                                                  float* __restrict__ t1)
{
    const int b = blockIdx.x, c = threadIdx.x;   // 512 threads
    __shared__ float sp[2048];
    for (int k = c; k < 2048; k += 512) sp[k] = pooled[(size_t)b * 2048 + k];
    __syncthreads();
    float acc = 0.f;
#pragma unroll 8
    for (int k = 0; k < 2048; ++k) acc = fmaf(sp[k], Wa[(size_t)k * 512 + c], acc);
    float s = g[c] * rsqrtf(var[c] + 1e-5f);
    float y = acc * s + (be[c] - mu[c] * s);
    t1[(size_t)b * 512 + c] = (y >= 0.f) ? y : 0.2f * y;
}

__global__ __launch_bounds__(256) void fc2_kernel(const float* __restrict__ t1,
                                                  const float* __restrict__ Wb,
                                                  const float* __restrict__ bias_b,
                                                  const float* __restrict__ g, const float* __restrict__ be,
                                                  const float* __restrict__ mu, const float* __restrict__ var,
                                                  float* __restrict__ t2)
{
    const int b = blockIdx.x, c = threadIdx.x;   // 256 threads
    __shared__ float sp[512];
    for (int k = c; k < 512; k += 256) sp[k] = t1[(size_t)b * 512 + k];
    __syncthreads();
    float acc = 0.f;
#pragma unroll 8
    for (int k = 0; k < 512; ++k) acc = fmaf(sp[k], Wb[(size_t)k * 256 + c], acc);
    acc += bias_b[c];
    float s = g[c] * rsqrtf(var[c] + 1e-5f);
    float y = acc * s + (be[c] - mu[c] * s);
    t2[(size_t)b * 256 + c] = (y >= 0.f) ? y : 0.2f * y;
}

__global__ __launch_bounds__(64) void fc3_kernel(const float* __restrict__ t2,
                                                 const float* __restrict__ Wc,
                                                 const float* __restrict__ bias_c,
                                                 float* __restrict__ out)
{
    const int b = blockIdx.x, c = threadIdx.x;
    __shared__ float sp[256];
    for (int k = c; k < 256; k += 64) sp[k] = t2[(size_t)b * 256 + k];
    __syncthreads();
    if (c < 40) {
        float acc = 0.f;
#pragma unroll 8
        for (int k = 0; k < 256; ++k) acc = fmaf(sp[k], Wc[(size_t)k * 40 + c], acc);
        out[(size_t)b * 40 + c] = acc + bias_c[c];
    }
}

// ======================= launch =======================
extern "C" void kernel_launch(void* const* d_in, const int* in_sizes, int n_in,
                              void* d_out, int out_size, void* d_ws, size_t ws_size,
                              hipStream_t stream)
{
    const float* pos = (const float*)d_in[0];
    const float* W1 = (const float*)d_in[1];
    const float* g1 = (const float*)d_in[2];  const float* be1 = (const float*)d_in[3];
    const float* mu1 = (const float*)d_in[4]; const float* va1 = (const float*)d_in[5];
    const float* W2 = (const float*)d_in[6];
    const float* g2 = (const float*)d_in[7];  const float* be2 = (const float*)d_in[8];
    const float* mu2 = (const float*)d_in[9]; const float* va2 = (const float*)d_in[10];
    const float* W3 = (const float*)d_in[11];
    const float* g3 = (const float*)d_in[12]; const float* be3 = (const float*)d_in[13];
    const float* mu3 = (const float*)d_in[14];const float* va3 = (const float*)d_in[15];
    const float* W4 = (const float*)d_in[16];
    const float* g4 = (const float*)d_in[17]; const float* be4 = (const float*)d_in[18];
    const float* mu4 = (const float*)d_in[19];const float* va4 = (const float*)d_in[20];
    const float* Wm = (const float*)d_in[21];
    const float* gm = (const float*)d_in[22]; const float* bem = (const float*)d_in[23];
    const float* mum = (const float*)d_in[24];const float* vam = (const float*)d_in[25];
    const float* Wa = (const float*)d_in[26];
    const float* ga = (const float*)d_in[27]; const float* bea = (const float*)d_in[28];
    const float* mua = (const float*)d_in[29];const float* vaa = (const float*)d_in[30];
    const float* Wb = (const float*)d_in[31];
    const float* gb = (const float*)d_in[32]; const float* beb = (const float*)d_in[33];
    const float* mub = (const float*)d_in[34];const float* vab = (const float*)d_in[35];
    const float* bias_b = (const float*)d_in[36];
    const float* Wc = (const float*)d_in[37];
    const float* bias_c = (const float*)d_in[38];

    char* ws = (char*)d_ws;
    size_t off = 0;
    auto alloc = [&](size_t bytes) -> void* {
        void* p = ws + off;
        off += (bytes + 255) & ~(size_t)255;
        return p;
    };
    float* xcat    = (float*)alloc((size_t)16384 * 512 * 4);
    float* sq      = (float*)alloc((size_t)16384 * 4);
    int*   idx     = (int*)  alloc((size_t)16384 * KNN * 4);
    float* apart   = (float*)alloc((size_t)16384 * 256 * 4);
    float* bpart   = (float*)alloc((size_t)16384 * 256 * 4);
    float* partmax = (float*)alloc((size_t)8 * 16 * 1024 * 4);
    float* partsum = (float*)alloc((size_t)8 * 16 * 1024 * 4);
    float* pooled  = (float*)alloc((size_t)8 * 2048 * 4);
    float* t1      = (float*)alloc((size_t)8 * 512 * 4);
    float* t2      = (float*)alloc((size_t)8 * 256 * 4);
    const size_t fixed = off;
    const size_t per_b = (size_t)NPTS * NPTS * 4;

    int CB; float* d2;
    if      (ws_size >= fixed + 8 * per_b) { CB = 8; d2 = (float*)(ws + fixed); }
    else if (ws_size >= fixed + 4 * per_b) { CB = 4; d2 = (float*)(ws + fixed); }
    else if (ws_size >= fixed + 2 * per_b) { CB = 2; d2 = (float*)(ws + fixed); }
    else { CB = 2; d2 = apart; }   // apart+bpart are contiguous, dead during dist/select phase

    struct LayerDesc {
        const float* xin; int lda; int F; int Fout;
        float* xout; const float* W;
        const float* g; const float* be; const float* mu; const float* va;
    };
    LayerDesc Ls[4] = {
        { pos,        3,   3,   64,  xcat + 0,   W1, g1, be1, mu1, va1 },
        { xcat + 0,   512, 64,  64,  xcat + 64,  W2, g2, be2, mu2, va2 },
        { xcat + 64,  512, 64,  128, xcat + 128, W3, g3, be3, mu3, va3 },
        { xcat + 128, 512, 128, 256, xcat + 256, W4, g4, be4, mu4, va4 },
    };

    for (int L = 0; L < 4; ++L) {
        const LayerDesc& ld = Ls[L];
        sq_kernel<<<64, 256, 0, stream>>>(ld.xin, ld.lda, ld.F, sq);
        for (int b0 = 0; b0 < BATCH; b0 += CB) {
            int cb = (BATCH - b0 < CB) ? (BATCH - b0) : CB;
            dist_kernel<<<dim3(16, 16, cb), 256, 0, stream>>>(ld.xin, ld.lda, sq, d2, ld.F, b0);
            select_kernel<<<dim3(NPTS, cb), 256, 0, stream>>>(d2, idx, b0);
        }
        gemm64_kernel<<<dim3(256, ld.Fout / 64), 256, 0, stream>>>(
            ld.xin, ld.lda, ld.F, ld.W, ld.Fout, apart, ld.Fout);
        gemm64_kernel<<<dim3(256, ld.Fout / 64), 256, 0, stream>>>(
            ld.xin, ld.lda, ld.F, ld.W + (size_t)ld.F * ld.Fout, ld.Fout, bpart, ld.Fout);
        aggregate_kernel<<<16384, ld.Fout, 0, stream>>>(
            apart, bpart, idx, ld.g, ld.be, ld.mu, ld.va, ld.xout, ld.Fout);
    }

    wm_pool_kernel<<<dim3(128, 8), 256, 0, stream>>>(xcat, Wm, gm, bem, mum, vam, partmax, partsum);
    pool2_kernel<<<dim3(4, 8), 256, 0, stream>>>(partmax, partsum, pooled);
    fc1_kernel<<<8, 512, 0, stream>>>(pooled, Wa, ga, bea, mua, vaa, t1);
    fc2_kernel<<<8, 256, 0, stream>>>(t1, Wb, bias_b, gb, beb, mub, vab, t2);
    fc3_kernel<<<8, 64, 0, stream>>>(t2, Wc, bias_c, (float*)d_out);
}